// Round 19
// baseline (146.247 us; speedup 1.0000x reference)
//
#include <hip/hip_runtime.h>

typedef unsigned short u16;
typedef unsigned int u32;
typedef __attribute__((ext_vector_type(4))) float f32x4;
typedef __attribute__((ext_vector_type(8))) __bf16 bf16x8;

#define L2E 1.4426950408889634f

__device__ __forceinline__ u16 f2bf(float f) { return __builtin_bit_cast(u16, (__bf16)f); }
__device__ __forceinline__ float bf2f(u16 h) { return (float)__builtin_bit_cast(__bf16, h); }
__device__ __forceinline__ f32x4 mfma16(bf16x8 a, bf16x8 b, f32x4 c) {
  return __builtin_amdgcn_mfma_f32_16x16x32_bf16(a, b, c, 0, 0, 0);
}
__device__ __forceinline__ void gl_lds16(const u16* g, u16* l) {
  __builtin_amdgcn_global_load_lds((__attribute__((address_space(1))) void*)g,
                                   (__attribute__((address_space(3))) void*)l,
                                   16, 0, 0);
}
__device__ __forceinline__ f32x4 fzero() {
  f32x4 v = {0.f, 0.f, 0.f, 0.f};
  return v;
}

__device__ __forceinline__ int rswz(int row) {
  return (((row >> 2) & 1) << 5) | (((row >> 3) & 1) << 6);
}

// ---------------- fused prep: x hi/lo split, Wq/Wk splits, Wv/Wo converts ----------------
__global__ void k_prep(const float* __restrict__ x, const float* __restrict__ Wq,
                       const float* __restrict__ Wk, const float* __restrict__ Wv,
                       const float* __restrict__ Wo,
                       u16* __restrict__ xh, u16* __restrict__ xl,
                       u16* __restrict__ wqh, u16* __restrict__ wql,
                       u16* __restrict__ wkh, u16* __restrict__ wkl,
                       u16* __restrict__ wvb, u16* __restrict__ wob) {
  int i = (blockIdx.x * 256 + threadIdx.x) * 4;
  const float* src;
  u16* hi;
  u16* lo;
  int j;
  if (i < 4194304)      { src = x;  hi = xh;  lo = xl;      j = i; }
  else if (i < 5242880) { src = Wq; hi = wqh; lo = wql;     j = i - 4194304; }
  else if (i < 6291456) { src = Wk; hi = wkh; lo = wkl;     j = i - 5242880; }
  else if (i < 7340032) { src = Wv; hi = wvb; lo = nullptr; j = i - 6291456; }
  else                  { src = Wo; hi = wob; lo = nullptr; j = i - 7340032; }
  float4 v = *(const float4*)(src + j);
  float vv[4] = {v.x, v.y, v.z, v.w};
  u16 hh[4];
#pragma unroll
  for (int t = 0; t < 4; ++t) hh[t] = f2bf(vv[t]);
  *(ushort4*)(hi + j) = make_ushort4(hh[0], hh[1], hh[2], hh[3]);
  if (lo) {
    u16 ll[4];
#pragma unroll
    for (int t = 0; t < 4; ++t) ll[t] = f2bf(vv[t] - bf2f(hh[t]));
    *(ushort4*)(lo + j) = make_ushort4(ll[0], ll[1], ll[2], ll[3]);
  }
}

// ---------------- GEMM body: 128x128, BK=64, 2-bit row swizzle (64.0us w/o setprio) ----------------
template <int SPLIT, int EPI>
__device__ __forceinline__ void gemm_body(
    u16* sm, const u16* __restrict__ Ah, const u16* __restrict__ Al,
    const u16* __restrict__ Bh, const u16* __restrict__ Bl,
    const float* __restrict__ bias, float scale,
    u16* __restrict__ oH, u16* __restrict__ oL, float* __restrict__ oF,
    int m0, int n0) {
  u16* sAh = sm;
  u16* sBh = sm + 8192;
  u16* sAl = SPLIT ? (sm + 16384) : sm;
  u16* sBl = SPLIT ? (sm + 24576) : sm;

  const int tid = threadIdx.x;
  const int lane = tid & 63, w = tid >> 6;
  const int wm = w >> 1, wn = w & 1;
  const int fr = lane & 15, fg = lane >> 4;
  const int strow = tid >> 3;
  const int stcb = (tid & 7) * 16;

  f32x4 acc[4][4];
#pragma unroll
  for (int i = 0; i < 4; ++i)
#pragma unroll
    for (int j = 0; j < 4; ++j) acc[i][j] = fzero();

  for (int kk = 0; kk < 1024; kk += 64) {
    __syncthreads();
#pragma unroll
    for (int c = 0; c < 4; ++c) {
      int row = c * 32 + strow;
      int srcc = (stcb ^ rswz(row)) >> 1;
      int dstc = row * 64 + (stcb >> 1);
      gl_lds16(Ah + (size_t)(m0 + row) * 1024 + kk + srcc, sAh + dstc);
      gl_lds16(Bh + (size_t)(n0 + row) * 1024 + kk + srcc, sBh + dstc);
      if constexpr (SPLIT) {
        gl_lds16(Al + (size_t)(m0 + row) * 1024 + kk + srcc, sAl + dstc);
        gl_lds16(Bl + (size_t)(n0 + row) * 1024 + kk + srcc, sBl + dstc);
      }
    }
    __syncthreads();

#pragma unroll
    for (int kk2 = 0; kk2 < 2; ++kk2) {
      bf16x8 ah[4], bh[4], al[4], bl[4];
#pragma unroll
      for (int i = 0; i < 4; ++i) {
        int ra = wm * 64 + i * 16 + fr;
        int ca = (kk2 * 64 + fg * 16) ^ rswz(ra);
        ah[i] = *(const bf16x8*)(sAh + ra * 64 + (ca >> 1));
        if constexpr (SPLIT) al[i] = *(const bf16x8*)(sAl + ra * 64 + (ca >> 1));
        int rb = wn * 64 + i * 16 + fr;
        int cb = (kk2 * 64 + fg * 16) ^ rswz(rb);
        bh[i] = *(const bf16x8*)(sBh + rb * 64 + (cb >> 1));
        if constexpr (SPLIT) bl[i] = *(const bf16x8*)(sBl + rb * 64 + (cb >> 1));
      }
#pragma unroll
      for (int i = 0; i < 4; ++i)
#pragma unroll
        for (int j = 0; j < 4; ++j) {
          acc[i][j] = mfma16(ah[i], bh[j], acc[i][j]);
          if constexpr (SPLIT) {
            acc[i][j] = mfma16(ah[i], bl[j], acc[i][j]);
            acc[i][j] = mfma16(al[i], bh[j], acc[i][j]);
          }
        }
    }
  }

#pragma unroll
  for (int i = 0; i < 4; ++i)
#pragma unroll
    for (int j = 0; j < 4; ++j) {
      int cg = n0 + wn * 64 + j * 16 + fr;
      float bv = bias[cg];
      if constexpr (EPI == 1) {
        int rgb = m0 + wm * 64 + i * 16 + fg * 4;
        int b = rgb >> 11, s = rgb & 2047, hd2 = cg >> 6, dd = cg & 63;
        u16 hv[4];
#pragma unroll
        for (int r = 0; r < 4; ++r) hv[r] = f2bf((acc[i][j][r] + bv) * scale);
        *(ushort4*)(oH + ((size_t)((b * 16 + hd2) * 64 + dd)) * 2048 + s) =
            make_ushort4(hv[0], hv[1], hv[2], hv[3]);
      } else {
#pragma unroll
        for (int r = 0; r < 4; ++r) {
          int rg = m0 + wm * 64 + i * 16 + fg * 4 + r;
          float val = (acc[i][j][r] + bv) * scale;
          if constexpr (EPI == 0) {
            int b = rg >> 11, s = rg & 2047, hd2 = cg >> 6, dd = cg & 63;
            size_t off = ((size_t)((b * 16 + hd2) * 2048 + s)) * 64 + dd;
            u16 hv = f2bf(val);
            oH[off] = hv;
            oL[off] = f2bf(val - bf2f(hv));
          } else {
            oF[(size_t)rg * 1024 + cg] = val;
          }
        }
      }
    }
}

// fused Q/K/V projection: 768 blocks; XCD-chunked so each XCD owns 4 m-tiles
__global__ __launch_bounds__(256, 2) void k_qkv(
    const u16* __restrict__ xh, const u16* __restrict__ xl,
    const u16* __restrict__ wqh, const u16* __restrict__ wql,
    const u16* __restrict__ wkh, const u16* __restrict__ wkl,
    const u16* __restrict__ wvb,
    const float* __restrict__ bq, const float* __restrict__ bk,
    const float* __restrict__ bv,
    u16* __restrict__ qh, u16* __restrict__ ql,
    u16* __restrict__ kh, u16* __restrict__ kl, u16* __restrict__ vt) {
  __shared__ u16 sm[32768];
  const int d = blockIdx.x;
  const int xcd = d & 7, j = d >> 3;
  const int m0 = (xcd * 4 + (j & 3)) * 128;
  const int pn = j >> 2;
  const int proj = pn >> 3, n0 = (pn & 7) * 128;
  if (proj == 0)
    gemm_body<1, 0>(sm, xh, xl, wqh, wql, bq, 0.125f * L2E, qh, ql, nullptr, m0, n0);
  else if (proj == 1)
    gemm_body<1, 0>(sm, xh, xl, wkh, wkl, bk, 1.0f, kh, kl, nullptr, m0, n0);
  else
    gemm_body<0, 1>(sm, xh, nullptr, wvb, nullptr, bv, 1.0f, vt, nullptr, nullptr, m0, n0);
}

// ---------------- o-proj: 64x128 tile, BK=64, swizzled; grid (64,8) ----------------
__global__ __launch_bounds__(256, 4) void k_oproj(
    const u16* __restrict__ A, const u16* __restrict__ B,
    const float* __restrict__ bias, float* __restrict__ out) {
  __shared__ u16 sm[12288];
  u16* sA = sm;
  u16* sB = sm + 4096;

  const int tid = threadIdx.x;
  const int lane = tid & 63, w = tid >> 6;
  const int fr = lane & 15, fg = lane >> 4;
  const int m0 = blockIdx.x * 64, n0 = blockIdx.y * 128;
  const int strow = tid >> 3;
  const int stcb = (tid & 7) * 16;

  f32x4 acc[4][2];
#pragma unroll
  for (int i = 0; i < 4; ++i)
#pragma unroll
    for (int jj = 0; jj < 2; ++jj) acc[i][jj] = fzero();

  for (int kk = 0; kk < 1024; kk += 64) {
    __syncthreads();
#pragma unroll
    for (int c = 0; c < 2; ++c) {
      int row = c * 32 + strow;
      int srcc = (stcb ^ rswz(row)) >> 1;
      gl_lds16(A + (size_t)(m0 + row) * 1024 + kk + srcc, sA + row * 64 + (stcb >> 1));
    }
#pragma unroll
    for (int c = 0; c < 4; ++c) {
      int row = c * 32 + strow;
      int srcc = (stcb ^ rswz(row)) >> 1;
      gl_lds16(B + (size_t)(n0 + row) * 1024 + kk + srcc, sB + row * 64 + (stcb >> 1));
    }
    __syncthreads();

#pragma unroll
    for (int kk2 = 0; kk2 < 2; ++kk2) {
      bf16x8 af[4], bf_[2];
#pragma unroll
      for (int i = 0; i < 4; ++i) {
        int ra = i * 16 + fr;
        int ca = (kk2 * 64 + fg * 16) ^ rswz(ra);
        af[i] = *(const bf16x8*)(sA + ra * 64 + (ca >> 1));
      }
#pragma unroll
      for (int jj = 0; jj < 2; ++jj) {
        int rb = w * 32 + jj * 16 + fr;
        int cb = (kk2 * 64 + fg * 16) ^ rswz(rb);
        bf_[jj] = *(const bf16x8*)(sB + rb * 64 + (cb >> 1));
      }
#pragma unroll
      for (int i = 0; i < 4; ++i)
#pragma unroll
        for (int jj = 0; jj < 2; ++jj) acc[i][jj] = mfma16(af[i], bf_[jj], acc[i][jj]);
    }
  }

#pragma unroll
  for (int i = 0; i < 4; ++i)
#pragma unroll
    for (int jj = 0; jj < 2; ++jj) {
      int cg = n0 + w * 32 + jj * 16 + fr;
      float bv = bias[cg];
#pragma unroll
      for (int r = 0; r < 4; ++r) {
        int rg = m0 + i * 16 + fg * 4 + r;
        out[(size_t)rg * 1024 + cg] = acc[i][jj][r] + bv;
      }
    }
}

// ---------------- flash attention (causal) ----------------
// R18 math; K hi/lo DOUBLE-buffered (32 KB), V SINGLE-buffered (8 KB) -> 40 KB
// -> 4 blocks/CU (16 waves). Per iter: STAGE_V(t) [post end-barrier of t-1, so
// PV(t-1) reads are done] -> STAGE_K(t+1) -> vmcnt(4) [queue K(t):4,V(t):2,K(t+1):4;
// drains K(t)+V(t)] -> barrier [all waves' stages visible] -> QK^T/softmax/PV ->
// end barrier. Same 2-barrier count as R11/R18.
__global__ __launch_bounds__(256, 4) void k_attn(
    const u16* __restrict__ Qh, const u16* __restrict__ Ql,
    const u16* __restrict__ Kh, const u16* __restrict__ Kl,
    const u16* __restrict__ Vt, u16* __restrict__ Oa) {
  __shared__ u16 sKh[2][4096], sKl[2][4096], sVt[4096];  // 40 KB

  const int tid = threadIdx.x;
  const int lane = tid & 63, w = tid >> 6;
  const int fr = lane & 15, fg = lane >> 4;

  const int d = blockIdx.x;
  const int bh = (d & 7) * 4 + ((d >> 3) & 3);
  const int j = 31 - (d >> 5);
  const int nt = j + 1;

  const size_t base = (size_t)bh * 131072;
  const u16* Qh_p = Qh + base;
  const u16* Ql_p = Ql + base;
  const u16* Kh_p = Kh + base;
  const u16* Kl_p = Kl + base;
  const u16* Vt_p = Vt + base;
  const int bb = bh >> 4, hh = bh & 15;

  const int srow = tid >> 3, scb8 = tid & 7;

  auto STAGE_K = [&](int t, int c) {
#pragma unroll
    for (int r2 = 0; r2 < 2; ++r2) {
      int prow = r2 * 32 + srow;
      int kvs = (prow & 32) | ((prow & 16) >> 2) | ((prow & 12) << 1) | (prow & 3);  // invpi
      int cbk = scb8 ^ (prow & 7);
      gl_lds16(Kh_p + ((size_t)(t * 64 + kvs)) * 64 + cbk * 8, &sKh[c][prow * 64 + scb8 * 8]);
      gl_lds16(Kl_p + ((size_t)(t * 64 + kvs)) * 64 + cbk * 8, &sKl[c][prow * 64 + scb8 * 8]);
    }
  };
  auto STAGE_V = [&](int t) {
#pragma unroll
    for (int r2 = 0; r2 < 2; ++r2) {
      int prow = r2 * 32 + srow;
      int cbk = scb8 ^ (prow & 7);
      gl_lds16(Vt_p + (size_t)prow * 2048 + t * 64 + cbk * 8, &sVt[prow * 64 + scb8 * 8]);
    }
  };

  const int qrow = j * 64 + w * 16 + fr;

  STAGE_K(0, 0);

  bf16x8 qhf[2], qlf[2];
#pragma unroll
  for (int ks = 0; ks < 2; ++ks) {
    qhf[ks] = *(const bf16x8*)(Qh_p + (size_t)qrow * 64 + ks * 32 + fg * 8);
    qlf[ks] = *(const bf16x8*)(Ql_p + (size_t)qrow * 64 + ks * 32 + fg * 8);
  }

  float mx = -1e30f, l = 0.f;
  f32x4 o[4];
#pragma unroll
  for (int f = 0; f < 4; ++f) o[f] = fzero();

  for (int t = 0; t < nt; ++t) {
    const int cur = t & 1;
    STAGE_V(t);  // safe: end-barrier of t-1 ensures PV(t-1) reads of sVt are done
    if (t + 1 < nt) {
      STAGE_K(t + 1, cur ^ 1);
      asm volatile("s_waitcnt vmcnt(4)" ::: "memory");  // drain K(t)+V(t); K(t+1) flies
    } else {
      asm volatile("s_waitcnt vmcnt(0)" ::: "memory");
    }
    asm volatile("s_barrier" ::: "memory");  // K(t), V(t) visible to all waves

    const u16* kbh = sKh[cur];
    const u16* kbl = sKl[cur];

    f32x4 sc[4];
    __builtin_amdgcn_s_setprio(1);
#pragma unroll
    for (int f = 0; f < 4; ++f) {
      f32x4 a = fzero();
#pragma unroll
      for (int ks = 0; ks < 2; ++ks) {
        int row = f * 16 + fr;
        int cb = (fg + 4 * ks) ^ (fr & 7);
        bf16x8 khv = *(const bf16x8*)(kbh + row * 64 + cb * 8);
        bf16x8 klv = *(const bf16x8*)(kbl + row * 64 + cb * 8);
        a = mfma16(khv, qhf[ks], a);
        a = mfma16(khv, qlf[ks], a);
        a = mfma16(klv, qhf[ks], a);
      }
      sc[f] = a;
    }
    __builtin_amdgcn_s_setprio(0);

    if (t == nt - 1) {  // diagonal tile: true kv = (f>>1)*32 + fg*8 + (f&1)*4 + r
#pragma unroll
      for (int f = 0; f < 4; ++f) {
        int kvb = t * 64 + (f >> 1) * 32 + fg * 8 + (f & 1) * 4;
#pragma unroll
        for (int r = 0; r < 4; ++r)
          if (kvb + r > qrow) sc[f][r] = -1e30f;
      }
    }

    float pm = -1e30f;
#pragma unroll
    for (int f = 0; f < 4; ++f)
#pragma unroll
      for (int r = 0; r < 4; ++r) pm = fmaxf(pm, sc[f][r]);
    pm = fmaxf(pm, __shfl_xor(pm, 16, 64));
    pm = fmaxf(pm, __shfl_xor(pm, 32, 64));

    const bool resc = __any(pm > mx + 11.5f);
    float alp = 1.0f;
    if (resc) {
      float mn = fmaxf(mx, pm);
      alp = exp2f(mx - mn);
      mx = mn;
    }

    float pp[4][4];
    float ps = 0.f;
#pragma unroll
    for (int f = 0; f < 4; ++f) {
#pragma unroll
      for (int r = 0; r < 4; ++r) {
        pp[f][r] = exp2f(sc[f][r] - mx);
        ps += pp[f][r];
      }
    }
    ps += __shfl_xor(ps, 16, 64);
    ps += __shfl_xor(ps, 32, 64);
    l = l * alp + ps;

    if (resc) {
      float alpb[4];
#pragma unroll
      for (int r = 0; r < 4; ++r) alpb[r] = __shfl(alp, fg * 4 + r, 64);
#pragma unroll
      for (int f = 0; f < 4; ++f)
#pragma unroll
        for (int r = 0; r < 4; ++r) o[f][r] *= alpb[r];
    }

    __builtin_amdgcn_s_setprio(1);
#pragma unroll
    for (int ks = 0; ks < 2; ++ks) {
      bf16x8 pa;
#pragma unroll
      for (int jj = 0; jj < 4; ++jj) {
        pa[jj] = (__bf16)pp[2 * ks][jj];
        pa[4 + jj] = (__bf16)pp[2 * ks + 1][jj];
      }
#pragma unroll
      for (int f = 0; f < 4; ++f) {
        int row = f * 16 + fr;
        int cb = (fg + 4 * ks) ^ (fr & 7);
        bf16x8 vb = *(const bf16x8*)(sVt + row * 64 + cb * 8);
        o[f] = mfma16(pa, vb, o[f]);
      }
    }
    __builtin_amdgcn_s_setprio(0);

    asm volatile("s_barrier" ::: "memory");  // sVt + sK[cur^1] reads done before restage
  }

  float lb[4];
#pragma unroll
  for (int r = 0; r < 4; ++r) lb[r] = __shfl(l, fg * 4 + r, 64);
#pragma unroll
  for (int f = 0; f < 4; ++f)
#pragma unroll
    for (int r = 0; r < 4; ++r) {
      int qg = j * 64 + w * 16 + fg * 4 + r;
      float val = o[f][r] / lb[r];
      Oa[((size_t)(bb * 2048 + qg)) * 1024 + hh * 64 + f * 16 + fr] = f2bf(val);
    }
}

// ---------------- launcher ----------------
extern "C" void kernel_launch(void* const* d_in, const int* in_sizes, int n_in,
                              void* d_out, int out_size, void* d_ws, size_t ws_size,
                              hipStream_t stream) {
  const float* x  = (const float*)d_in[0];
  const float* Wq = (const float*)d_in[1];
  const float* bq = (const float*)d_in[2];
  const float* Wk = (const float*)d_in[3];
  const float* bk = (const float*)d_in[4];
  const float* Wv = (const float*)d_in[5];
  const float* bv = (const float*)d_in[6];
  const float* Wo = (const float*)d_in[7];
  const float* bo = (const float*)d_in[8];
  float* out = (float*)d_out;

  u16* ws  = (u16*)d_ws;
  u16* xh  = ws;
  u16* xl  = xh + 4194304;
  u16* wqh = xl + 4194304;
  u16* wql = wqh + 1048576;
  u16* wkh = wql + 1048576;
  u16* wkl = wkh + 1048576;
  u16* wvb = wkl + 1048576;
  u16* wob = wvb + 1048576;
  u16* qh  = wob + 1048576;
  u16* ql  = qh + 4194304;
  u16* kh  = ql + 4194304;
  u16* kl  = kh + 4194304;
  u16* vt  = kl + 4194304;
  u16* ao  = xh;  // x_hi dead after projections; reuse for attention output

  k_prep<<<8192, 256, 0, stream>>>(x, Wq, Wk, Wv, Wo, xh, xl, wqh, wql, wkh, wkl, wvb, wob);
  k_qkv<<<768, 256, 0, stream>>>(xh, xl, wqh, wql, wkh, wkl, wvb, bq, bk, bv,
                                 qh, ql, kh, kl, vt);
  k_attn<<<1024, 256, 0, stream>>>(qh, ql, kh, kl, vt, ao);
  k_oproj<<<dim3(64, 8), 256, 0, stream>>>(ao, wob, bo, out);
}

// Round 20
// 144.610 us; speedup vs baseline: 1.0113x; 1.0113x over previous
//
#include <hip/hip_runtime.h>

typedef unsigned short u16;
typedef unsigned int u32;
typedef __attribute__((ext_vector_type(4))) float f32x4;
typedef __attribute__((ext_vector_type(8))) __bf16 bf16x8;

#define L2E 1.4426950408889634f

__device__ __forceinline__ u16 f2bf(float f) { return __builtin_bit_cast(u16, (__bf16)f); }
__device__ __forceinline__ float bf2f(u16 h) { return (float)__builtin_bit_cast(__bf16, h); }
__device__ __forceinline__ f32x4 mfma16(bf16x8 a, bf16x8 b, f32x4 c) {
  return __builtin_amdgcn_mfma_f32_16x16x32_bf16(a, b, c, 0, 0, 0);
}
__device__ __forceinline__ void gl_lds16(const u16* g, u16* l) {
  __builtin_amdgcn_global_load_lds((__attribute__((address_space(1))) void*)g,
                                   (__attribute__((address_space(3))) void*)l,
                                   16, 0, 0);
}
__device__ __forceinline__ f32x4 fzero() {
  f32x4 v = {0.f, 0.f, 0.f, 0.f};
  return v;
}

__device__ __forceinline__ int rswz(int row) {
  return (((row >> 2) & 1) << 5) | (((row >> 3) & 1) << 6);
}

// ---------------- fused prep: x hi/lo split, Wq/Wk splits, Wv/Wo converts ----------------
__global__ void k_prep(const float* __restrict__ x, const float* __restrict__ Wq,
                       const float* __restrict__ Wk, const float* __restrict__ Wv,
                       const float* __restrict__ Wo,
                       u16* __restrict__ xh, u16* __restrict__ xl,
                       u16* __restrict__ wqh, u16* __restrict__ wql,
                       u16* __restrict__ wkh, u16* __restrict__ wkl,
                       u16* __restrict__ wvb, u16* __restrict__ wob) {
  int i = (blockIdx.x * 256 + threadIdx.x) * 4;
  const float* src;
  u16* hi;
  u16* lo;
  int j;
  if (i < 4194304)      { src = x;  hi = xh;  lo = xl;      j = i; }
  else if (i < 5242880) { src = Wq; hi = wqh; lo = wql;     j = i - 4194304; }
  else if (i < 6291456) { src = Wk; hi = wkh; lo = wkl;     j = i - 5242880; }
  else if (i < 7340032) { src = Wv; hi = wvb; lo = nullptr; j = i - 6291456; }
  else                  { src = Wo; hi = wob; lo = nullptr; j = i - 7340032; }
  float4 v = *(const float4*)(src + j);
  float vv[4] = {v.x, v.y, v.z, v.w};
  u16 hh[4];
#pragma unroll
  for (int t = 0; t < 4; ++t) hh[t] = f2bf(vv[t]);
  *(ushort4*)(hi + j) = make_ushort4(hh[0], hh[1], hh[2], hh[3]);
  if (lo) {
    u16 ll[4];
#pragma unroll
    for (int t = 0; t < 4; ++t) ll[t] = f2bf(vv[t] - bf2f(hh[t]));
    *(ushort4*)(lo + j) = make_ushort4(ll[0], ll[1], ll[2], ll[3]);
  }
}

// ---------------- GEMM body: 128x128, BK=64, 2-bit row swizzle, no setprio ----------------
template <int SPLIT, int EPI>
__device__ __forceinline__ void gemm_body(
    u16* sm, const u16* __restrict__ Ah, const u16* __restrict__ Al,
    const u16* __restrict__ Bh, const u16* __restrict__ Bl,
    const float* __restrict__ bias, float scale,
    u16* __restrict__ oH, u16* __restrict__ oL, float* __restrict__ oF,
    int m0, int n0) {
  u16* sAh = sm;
  u16* sBh = sm + 8192;
  u16* sAl = SPLIT ? (sm + 16384) : sm;
  u16* sBl = SPLIT ? (sm + 24576) : sm;

  const int tid = threadIdx.x;
  const int lane = tid & 63, w = tid >> 6;
  const int wm = w >> 1, wn = w & 1;
  const int fr = lane & 15, fg = lane >> 4;
  const int strow = tid >> 3;
  const int stcb = (tid & 7) * 16;

  f32x4 acc[4][4];
#pragma unroll
  for (int i = 0; i < 4; ++i)
#pragma unroll
    for (int j = 0; j < 4; ++j) acc[i][j] = fzero();

  for (int kk = 0; kk < 1024; kk += 64) {
    __syncthreads();
#pragma unroll
    for (int c = 0; c < 4; ++c) {
      int row = c * 32 + strow;
      int srcc = (stcb ^ rswz(row)) >> 1;
      int dstc = row * 64 + (stcb >> 1);
      gl_lds16(Ah + (size_t)(m0 + row) * 1024 + kk + srcc, sAh + dstc);
      gl_lds16(Bh + (size_t)(n0 + row) * 1024 + kk + srcc, sBh + dstc);
      if constexpr (SPLIT) {
        gl_lds16(Al + (size_t)(m0 + row) * 1024 + kk + srcc, sAl + dstc);
        gl_lds16(Bl + (size_t)(n0 + row) * 1024 + kk + srcc, sBl + dstc);
      }
    }
    __syncthreads();

#pragma unroll
    for (int kk2 = 0; kk2 < 2; ++kk2) {
      bf16x8 ah[4], bh[4], al[4], bl[4];
#pragma unroll
      for (int i = 0; i < 4; ++i) {
        int ra = wm * 64 + i * 16 + fr;
        int ca = (kk2 * 64 + fg * 16) ^ rswz(ra);
        ah[i] = *(const bf16x8*)(sAh + ra * 64 + (ca >> 1));
        if constexpr (SPLIT) al[i] = *(const bf16x8*)(sAl + ra * 64 + (ca >> 1));
        int rb = wn * 64 + i * 16 + fr;
        int cb = (kk2 * 64 + fg * 16) ^ rswz(rb);
        bh[i] = *(const bf16x8*)(sBh + rb * 64 + (cb >> 1));
        if constexpr (SPLIT) bl[i] = *(const bf16x8*)(sBl + rb * 64 + (cb >> 1));
      }
#pragma unroll
      for (int i = 0; i < 4; ++i)
#pragma unroll
        for (int j = 0; j < 4; ++j) {
          acc[i][j] = mfma16(ah[i], bh[j], acc[i][j]);
          if constexpr (SPLIT) {
            acc[i][j] = mfma16(ah[i], bl[j], acc[i][j]);
            acc[i][j] = mfma16(al[i], bh[j], acc[i][j]);
          }
        }
    }
  }

#pragma unroll
  for (int i = 0; i < 4; ++i)
#pragma unroll
    for (int j = 0; j < 4; ++j) {
      int cg = n0 + wn * 64 + j * 16 + fr;
      float bv = bias[cg];
      if constexpr (EPI == 1) {
        int rgb = m0 + wm * 64 + i * 16 + fg * 4;
        int b = rgb >> 11, s = rgb & 2047, hd2 = cg >> 6, dd = cg & 63;
        u16 hv[4];
#pragma unroll
        for (int r = 0; r < 4; ++r) hv[r] = f2bf((acc[i][j][r] + bv) * scale);
        *(ushort4*)(oH + ((size_t)((b * 16 + hd2) * 64 + dd)) * 2048 + s) =
            make_ushort4(hv[0], hv[1], hv[2], hv[3]);
      } else {
#pragma unroll
        for (int r = 0; r < 4; ++r) {
          int rg = m0 + wm * 64 + i * 16 + fg * 4 + r;
          float val = (acc[i][j][r] + bv) * scale;
          if constexpr (EPI == 0) {
            int b = rg >> 11, s = rg & 2047, hd2 = cg >> 6, dd = cg & 63;
            size_t off = ((size_t)((b * 16 + hd2) * 2048 + s)) * 64 + dd;
            u16 hv = f2bf(val);
            oH[off] = hv;
            oL[off] = f2bf(val - bf2f(hv));
          } else {
            oF[(size_t)rg * 1024 + cg] = val;
          }
        }
      }
    }
}

// fused Q/K/V projection: 768 blocks; XCD-chunked so each XCD owns 4 m-tiles
__global__ __launch_bounds__(256, 2) void k_qkv(
    const u16* __restrict__ xh, const u16* __restrict__ xl,
    const u16* __restrict__ wqh, const u16* __restrict__ wql,
    const u16* __restrict__ wkh, const u16* __restrict__ wkl,
    const u16* __restrict__ wvb,
    const float* __restrict__ bq, const float* __restrict__ bk,
    const float* __restrict__ bv,
    u16* __restrict__ qh, u16* __restrict__ ql,
    u16* __restrict__ kh, u16* __restrict__ kl, u16* __restrict__ vt) {
  __shared__ u16 sm[32768];
  const int d = blockIdx.x;
  const int xcd = d & 7, j = d >> 3;
  const int m0 = (xcd * 4 + (j & 3)) * 128;
  const int pn = j >> 2;
  const int proj = pn >> 3, n0 = (pn & 7) * 128;
  if (proj == 0)
    gemm_body<1, 0>(sm, xh, xl, wqh, wql, bq, 0.125f * L2E, qh, ql, nullptr, m0, n0);
  else if (proj == 1)
    gemm_body<1, 0>(sm, xh, xl, wkh, wkl, bk, 1.0f, kh, kl, nullptr, m0, n0);
  else
    gemm_body<0, 1>(sm, xh, nullptr, wvb, nullptr, bv, 1.0f, vt, nullptr, nullptr, m0, n0);
}

// ---------------- o-proj: 64x128 tile, BK=64, swizzled; grid (64,8) ----------------
__global__ __launch_bounds__(256, 4) void k_oproj(
    const u16* __restrict__ A, const u16* __restrict__ B,
    const float* __restrict__ bias, float* __restrict__ out) {
  __shared__ u16 sm[12288];
  u16* sA = sm;
  u16* sB = sm + 4096;

  const int tid = threadIdx.x;
  const int lane = tid & 63, w = tid >> 6;
  const int fr = lane & 15, fg = lane >> 4;
  const int m0 = blockIdx.x * 64, n0 = blockIdx.y * 128;
  const int strow = tid >> 3;
  const int stcb = (tid & 7) * 16;

  f32x4 acc[4][2];
#pragma unroll
  for (int i = 0; i < 4; ++i)
#pragma unroll
    for (int jj = 0; jj < 2; ++jj) acc[i][jj] = fzero();

  for (int kk = 0; kk < 1024; kk += 64) {
    __syncthreads();
#pragma unroll
    for (int c = 0; c < 2; ++c) {
      int row = c * 32 + strow;
      int srcc = (stcb ^ rswz(row)) >> 1;
      gl_lds16(A + (size_t)(m0 + row) * 1024 + kk + srcc, sA + row * 64 + (stcb >> 1));
    }
#pragma unroll
    for (int c = 0; c < 4; ++c) {
      int row = c * 32 + strow;
      int srcc = (stcb ^ rswz(row)) >> 1;
      gl_lds16(B + (size_t)(n0 + row) * 1024 + kk + srcc, sB + row * 64 + (stcb >> 1));
    }
    __syncthreads();

#pragma unroll
    for (int kk2 = 0; kk2 < 2; ++kk2) {
      bf16x8 af[4], bf_[2];
#pragma unroll
      for (int i = 0; i < 4; ++i) {
        int ra = i * 16 + fr;
        int ca = (kk2 * 64 + fg * 16) ^ rswz(ra);
        af[i] = *(const bf16x8*)(sA + ra * 64 + (ca >> 1));
      }
#pragma unroll
      for (int jj = 0; jj < 2; ++jj) {
        int rb = w * 32 + jj * 16 + fr;
        int cb = (kk2 * 64 + fg * 16) ^ rswz(rb);
        bf_[jj] = *(const bf16x8*)(sB + rb * 64 + (cb >> 1));
      }
#pragma unroll
      for (int i = 0; i < 4; ++i)
#pragma unroll
        for (int jj = 0; jj < 2; ++jj) acc[i][jj] = mfma16(af[i], bf_[jj], acc[i][jj]);
    }
  }

#pragma unroll
  for (int i = 0; i < 4; ++i)
#pragma unroll
    for (int jj = 0; jj < 2; ++jj) {
      int cg = n0 + w * 32 + jj * 16 + fr;
      float bv = bias[cg];
#pragma unroll
      for (int r = 0; r < 4; ++r) {
        int rg = m0 + i * 16 + fg * 4 + r;
        out[(size_t)rg * 1024 + cg] = acc[i][jj][r] + bv;
      }
    }
}

// ---------------- flash attention (causal) — R18 config (session best) ----------------
// 256 threads = 4 waves, QBLK=64, ONE q-tile per block. Grid 1024, longest-j-first.
// K/V double-buffered (48 KB) + 2 barriers/iter -> 3 blocks/CU resident.
// K rows source-permuted (invpi) so lane's QK^T outputs ARE the PV A-fragment.
// setprio kept (phase-diverse blocks = m191 positive regime).
__global__ __launch_bounds__(256, 3) void k_attn(
    const u16* __restrict__ Qh, const u16* __restrict__ Ql,
    const u16* __restrict__ Kh, const u16* __restrict__ Kl,
    const u16* __restrict__ Vt, u16* __restrict__ Oa) {
  __shared__ u16 sKh[2][4096], sKl[2][4096], sVt[2][4096];  // 48 KB

  const int tid = threadIdx.x;
  const int lane = tid & 63, w = tid >> 6;
  const int fr = lane & 15, fg = lane >> 4;

  const int d = blockIdx.x;
  const int bh = (d & 7) * 4 + ((d >> 3) & 3);
  const int j = 31 - (d >> 5);
  const int nt = j + 1;

  const size_t base = (size_t)bh * 131072;
  const u16* Qh_p = Qh + base;
  const u16* Ql_p = Ql + base;
  const u16* Kh_p = Kh + base;
  const u16* Kl_p = Kl + base;
  const u16* Vt_p = Vt + base;
  const int bb = bh >> 4, hh = bh & 15;

  const int srow = tid >> 3, scb8 = tid & 7;

  auto STAGE = [&](int t, int c) {
#pragma unroll
    for (int r2 = 0; r2 < 2; ++r2) {
      int prow = r2 * 32 + srow;
      int kvs = (prow & 32) | ((prow & 16) >> 2) | ((prow & 12) << 1) | (prow & 3);  // invpi
      int cbk = scb8 ^ (prow & 7);
      gl_lds16(Kh_p + ((size_t)(t * 64 + kvs)) * 64 + cbk * 8, &sKh[c][prow * 64 + scb8 * 8]);
      gl_lds16(Kl_p + ((size_t)(t * 64 + kvs)) * 64 + cbk * 8, &sKl[c][prow * 64 + scb8 * 8]);
      gl_lds16(Vt_p + (size_t)prow * 2048 + t * 64 + cbk * 8, &sVt[c][prow * 64 + scb8 * 8]);
    }
  };

  const int qrow = j * 64 + w * 16 + fr;

  STAGE(0, 0);

  bf16x8 qhf[2], qlf[2];
#pragma unroll
  for (int ks = 0; ks < 2; ++ks) {
    qhf[ks] = *(const bf16x8*)(Qh_p + (size_t)qrow * 64 + ks * 32 + fg * 8);
    qlf[ks] = *(const bf16x8*)(Ql_p + (size_t)qrow * 64 + ks * 32 + fg * 8);
  }

  float mx = -1e30f, l = 0.f;
  f32x4 o[4];
#pragma unroll
  for (int f = 0; f < 4; ++f) o[f] = fzero();

  for (int t = 0; t < nt; ++t) {
    const int cur = t & 1;
    if (t + 1 < nt) {
      STAGE(t + 1, cur ^ 1);
      asm volatile("s_waitcnt vmcnt(6)" ::: "memory");
    } else {
      asm volatile("s_waitcnt vmcnt(0)" ::: "memory");
    }
    asm volatile("s_barrier" ::: "memory");

    const u16* kbh = sKh[cur];
    const u16* kbl = sKl[cur];
    const u16* vbb = sVt[cur];

    f32x4 sc[4];
    __builtin_amdgcn_s_setprio(1);
#pragma unroll
    for (int f = 0; f < 4; ++f) {
      f32x4 a = fzero();
#pragma unroll
      for (int ks = 0; ks < 2; ++ks) {
        int row = f * 16 + fr;
        int cb = (fg + 4 * ks) ^ (fr & 7);
        bf16x8 khv = *(const bf16x8*)(kbh + row * 64 + cb * 8);
        bf16x8 klv = *(const bf16x8*)(kbl + row * 64 + cb * 8);
        a = mfma16(khv, qhf[ks], a);
        a = mfma16(khv, qlf[ks], a);
        a = mfma16(klv, qhf[ks], a);
      }
      sc[f] = a;
    }
    __builtin_amdgcn_s_setprio(0);

    if (t == nt - 1) {
#pragma unroll
      for (int f = 0; f < 4; ++f) {
        int kvb = t * 64 + (f >> 1) * 32 + fg * 8 + (f & 1) * 4;
#pragma unroll
        for (int r = 0; r < 4; ++r)
          if (kvb + r > qrow) sc[f][r] = -1e30f;
      }
    }

    float pm = -1e30f;
#pragma unroll
    for (int f = 0; f < 4; ++f)
#pragma unroll
      for (int r = 0; r < 4; ++r) pm = fmaxf(pm, sc[f][r]);
    pm = fmaxf(pm, __shfl_xor(pm, 16, 64));
    pm = fmaxf(pm, __shfl_xor(pm, 32, 64));

    const bool resc = __any(pm > mx + 11.5f);
    float alp = 1.0f;
    if (resc) {
      float mn = fmaxf(mx, pm);
      alp = exp2f(mx - mn);
      mx = mn;
    }

    float pp[4][4];
    float ps = 0.f;
#pragma unroll
    for (int f = 0; f < 4; ++f) {
#pragma unroll
      for (int r = 0; r < 4; ++r) {
        pp[f][r] = exp2f(sc[f][r] - mx);
        ps += pp[f][r];
      }
    }
    ps += __shfl_xor(ps, 16, 64);
    ps += __shfl_xor(ps, 32, 64);
    l = l * alp + ps;

    if (resc) {
      float alpb[4];
#pragma unroll
      for (int r = 0; r < 4; ++r) alpb[r] = __shfl(alp, fg * 4 + r, 64);
#pragma unroll
      for (int f = 0; f < 4; ++f)
#pragma unroll
        for (int r = 0; r < 4; ++r) o[f][r] *= alpb[r];
    }

    __builtin_amdgcn_s_setprio(1);
#pragma unroll
    for (int ks = 0; ks < 2; ++ks) {
      bf16x8 pa;
#pragma unroll
      for (int jj = 0; jj < 4; ++jj) {
        pa[jj] = (__bf16)pp[2 * ks][jj];
        pa[4 + jj] = (__bf16)pp[2 * ks + 1][jj];
      }
#pragma unroll
      for (int f = 0; f < 4; ++f) {
        int row = f * 16 + fr;
        int cb = (fg + 4 * ks) ^ (fr & 7);
        bf16x8 vb = *(const bf16x8*)(vbb + row * 64 + cb * 8);
        o[f] = mfma16(pa, vb, o[f]);
      }
    }
    __builtin_amdgcn_s_setprio(0);

    asm volatile("s_barrier" ::: "memory");
  }

  float lb[4];
#pragma unroll
  for (int r = 0; r < 4; ++r) lb[r] = __shfl(l, fg * 4 + r, 64);
#pragma unroll
  for (int f = 0; f < 4; ++f)
#pragma unroll
    for (int r = 0; r < 4; ++r) {
      int qg = j * 64 + w * 16 + fg * 4 + r;
      float val = o[f][r] / lb[r];
      Oa[((size_t)(bb * 2048 + qg)) * 1024 + hh * 64 + f * 16 + fr] = f2bf(val);
    }
}

// ---------------- launcher ----------------
extern "C" void kernel_launch(void* const* d_in, const int* in_sizes, int n_in,
                              void* d_out, int out_size, void* d_ws, size_t ws_size,
                              hipStream_t stream) {
  const float* x  = (const float*)d_in[0];
  const float* Wq = (const float*)d_in[1];
  const float* bq = (const float*)d_in[2];
  const float* Wk = (const float*)d_in[3];
  const float* bk = (const float*)d_in[4];
  const float* Wv = (const float*)d_in[5];
  const float* bv = (const float*)d_in[6];
  const float* Wo = (const float*)d_in[7];
  const float* bo = (const float*)d_in[8];
  float* out = (float*)d_out;

  u16* ws  = (u16*)d_ws;
  u16* xh  = ws;
  u16* xl  = xh + 4194304;
  u16* wqh = xl + 4194304;
  u16* wql = wqh + 1048576;
  u16* wkh = wql + 1048576;
  u16* wkl = wkh + 1048576;
  u16* wvb = wkl + 1048576;
  u16* wob = wvb + 1048576;
  u16* qh  = wob + 1048576;
  u16* ql  = qh + 4194304;
  u16* kh  = ql + 4194304;
  u16* kl  = kh + 4194304;
  u16* vt  = kl + 4194304;
  u16* ao  = xh;  // x_hi dead after projections; reuse for attention output

  k_prep<<<8192, 256, 0, stream>>>(x, Wq, Wk, Wv, Wo, xh, xl, wqh, wql, wkh, wkl, wvb, wob);
  k_qkv<<<768, 256, 0, stream>>>(xh, xl, wqh, wql, wkh, wkl, wvb, bq, bk, bv,
                                 qh, ql, kh, kl, vt);
  k_attn<<<1024, 256, 0, stream>>>(qh, ql, kh, kl, vt, ao);
  k_oproj<<<dim3(64, 8), 256, 0, stream>>>(ao, wob, bo, out);
}